// Round 14
// baseline (422.095 us; speedup 1.0000x reference)
//
#include <hip/hip_runtime.h>
#include <math.h>

// x: (4,16,256,32,64) f32 -> NS=64 samples, CD=256 channels, HW=2048 positions
#define NS 64
#define CD 256
#define HW 2048
#define MD 1024
#define SAMPLE (CD * HW)
#define LN_EPS 1e-5f

#define PB 64            // positions per block (4 pair-strips x 16p)
#define MC 32            // m-chunk
#define NCH (MD / MC)    // 32 chunks

typedef float f32x4 __attribute__((ext_vector_type(4)));
typedef long i64;

// Rotated 4-bit XOR swizzle for Ysh (bits 3-6).
__device__ __forceinline__ int swz(int p) {
  int k = (p ^ (p >> 2)) & 15;
  return ((k & 7) << 4) | (k & 8);
}

// ------------- merged: weight prep (fp8 frag-packed) + LN stats stage 1 -------------
// blocks 0..511: stats1 slices; blocks 512..1023: prep (r10/r12 fragment layout).
__global__ __launch_bounds__(256) void k_prep_stats(
    const float* __restrict__ x, const float* __restrict__ w_in,
    const float* __restrict__ w_out, unsigned char* __restrict__ w_in8p,
    unsigned char* __restrict__ w_out8p, double* __restrict__ partial) {
  if (blockIdx.x < 512) {
    int s = blockIdx.x >> 3, sl = blockIdx.x & 7;
    const float4* p = (const float4*)(x + (size_t)s * SAMPLE + (size_t)sl * 65536);
    double sum = 0.0, ssq = 0.0;
    for (int i = 0; i < 64; ++i) {
      float4 v = p[i * 256 + threadIdx.x];
      sum += (double)v.x + (double)v.y + (double)v.z + (double)v.w;
      ssq += (double)v.x * v.x + (double)v.y * v.y + (double)v.z * v.z + (double)v.w * v.w;
    }
    for (int off = 32; off; off >>= 1) {
      sum += __shfl_down(sum, off);
      ssq += __shfl_down(ssq, off);
    }
    __shared__ double red[4][2];
    int wv = threadIdx.x >> 6, ln = threadIdx.x & 63;
    if (ln == 0) { red[wv][0] = sum; red[wv][1] = ssq; }
    __syncthreads();
    if (threadIdx.x == 0) {
      for (int i = 1; i < 4; ++i) { sum += red[i][0]; ssq += red[i][1]; }
      partial[blockIdx.x * 2] = sum;
      partial[blockIdx.x * 2 + 1] = ssq;
    }
  } else {
    int id = (blockIdx.x - 512) * 256 + threadIdx.x;  // 0..131071
    if (id < 65536) {
      int i = id;
      int f = i >> 7, l = (i >> 1) & 63, j0 = (i & 1) * 4;
      int m = (f >> 3) * 16 + (l & 15);
      int c0 = (f & 7) * 32 + (l >> 4) * 8 + j0;
      float a = w_in[(size_t)(c0 + 0) * MD + m];
      float b = w_in[(size_t)(c0 + 1) * MD + m];
      float c = w_in[(size_t)(c0 + 2) * MD + m];
      float d = w_in[(size_t)(c0 + 3) * MD + m];
      int r = __builtin_amdgcn_cvt_pk_fp8_f32(a, b, 0, false);
      r = __builtin_amdgcn_cvt_pk_fp8_f32(c, d, r, true);
      ((int*)w_in8p)[i] = r;
    } else {
      int i = id - 65536;
      int g = i >> 7, l = (i >> 1) & 63, j0 = (i & 1) * 4;
      int c = (g & 15) * 16 + (l & 15);
      int m0 = (g >> 4) * 32 + (l >> 4) * 8 + j0;
      float a = w_out[(size_t)(m0 + 0) * CD + c];
      float b = w_out[(size_t)(m0 + 1) * CD + c];
      float cc = w_out[(size_t)(m0 + 2) * CD + c];
      float d = w_out[(size_t)(m0 + 3) * CD + c];
      int r = __builtin_amdgcn_cvt_pk_fp8_f32(a, b, 0, false);
      r = __builtin_amdgcn_cvt_pk_fp8_f32(cc, d, r, true);
      ((int*)w_out8p)[i] = r;
    }
  }
}

// ---------------- LN stats, stage 2 ----------------
__global__ void k_stats2(const double* __restrict__ partial, float* __restrict__ stats) {
  int s = threadIdx.x;  // 64 threads
  double sum = 0.0, ssq = 0.0;
  for (int i = 0; i < 8; ++i) {
    sum += partial[(s * 8 + i) * 2];
    ssq += partial[(s * 8 + i) * 2 + 1];
  }
  double mean = sum / (double)SAMPLE;
  double var = ssq / (double)SAMPLE - mean * mean;
  stats[s * 2] = (float)mean;
  stats[s * 2 + 1] = (float)(1.0 / sqrt(var + (double)LN_EPS));
}

// ---------------- fused LN + MLP + layer-scale + residual ----------------
// r13 pair-split structure, but weights are read DIRECTLY FROM GLOBAL into
// registers (frag-packed, coalesced 512B/frag, L1/L2-resident): the LDS pipe
// was ~55% busy serving 16 of 18 LDS ops/wave/chunk for weight fragments
// (LDS has no cross-wave broadcast -> 4x redundancy). Now LDS carries only
// Ysh staging + the 2-op/chunk Texch pair-handoff (~8% pipe). No weight
// staging, no DMA, no multi-buffer protocol; barriers remain for Texch only
// and drain nothing (vmcnt consumed by GEMM2 pre-barrier). W2(ch-1) loads
// issue after GEMM1 so GELU covers their L2 latency (T14).
__global__ __launch_bounds__(512, 6) void k_fused(
    const float* __restrict__ x, const float* __restrict__ ln_w, const float* __restrict__ ln_b,
    const float* __restrict__ b_in, const float* __restrict__ b_out, const float* __restrict__ gamma,
    const unsigned char* __restrict__ w_in8p, const unsigned char* __restrict__ w_out8p,
    const float* __restrict__ stats, float* __restrict__ out) {
  __shared__ unsigned char smem[20480];   // Ysh 16K | Texch 2x2K
  unsigned char* Ysh = smem;

  const int tid = threadIdx.x;
  const int lane = tid & 63, l15 = lane & 15, l4 = lane >> 4;
  const int wv = tid >> 6;                 // 0..7
  const int q = wv >> 1, h = wv & 1;       // pair, c/m half
  const int s = blockIdx.x >> 5;
  const int p0 = (blockIdx.x & 31) * PB;
  const float mu = stats[s * 2], rstd = stats[s * 2 + 1];
  const float a_ln = rstd, c_ln = -mu * rstd;
  const size_t xbase = (size_t)s * SAMPLE;

  // ---- stage Ysh: normalize + affine, transpose (c,p)->(p,c), cvt fp8 ----
  #pragma unroll
  for (int it = 0; it < 2; ++it) {
    int bid = it * 512 + tid;               // 1024 4x4 micro-blocks
    int c0 = (bid >> 4) * 4, pp = (bid & 15) * 4;
    float yv[4][4];
    #pragma unroll
    for (int i = 0; i < 4; ++i) {
      size_t off = (size_t)(c0 + i) * HW + p0 + pp;
      float4 xv = *(const float4*)(x + xbase + off);
      float4 lw = *(const float4*)(ln_w + off);
      float4 lb = *(const float4*)(ln_b + off);
      yv[i][0] = fmaf(fmaf(xv.x, a_ln, c_ln), lw.x, lb.x);
      yv[i][1] = fmaf(fmaf(xv.y, a_ln, c_ln), lw.y, lb.y);
      yv[i][2] = fmaf(fmaf(xv.z, a_ln, c_ln), lw.z, lb.z);
      yv[i][3] = fmaf(fmaf(xv.w, a_ln, c_ln), lw.w, lb.w);
    }
    #pragma unroll
    for (int j = 0; j < 4; ++j) {
      int p = pp + j;
      int r = __builtin_amdgcn_cvt_pk_fp8_f32(yv[0][j], yv[1][j], 0, false);
      r = __builtin_amdgcn_cvt_pk_fp8_f32(yv[2][j], yv[3][j], r, true);
      *(int*)&Ysh[p * 256 + (c0 ^ swz(p))] = r;
    }
  }

  const int strip = q * 16;                // pair's p-strip
  const int pY = strip + l15;              // Ysh row this lane reads
  const int sY = swz(pY);
  f32x4 acc2[8] = {};                      // 16p x 128c per wave (8 c-tiles)

  __syncthreads();  // Ysh visible across waves

  // ---- breg: the pair's ENTIRE Ysh slice -> 8 i64 registers ----
  i64 breg[8];
  #pragma unroll
  for (int kk = 0; kk < 8; ++kk)
    breg[kk] = *(const i64*)&Ysh[pY * 256 + ((kk * 32 + l4 * 8) ^ sY)];

  // Texch addressing (r13-verified swizzle): writer holds T[p=strip+l15][m=h*16+l4*4..+3]
  const int exw = ((((h * 16 + l4 * 4) >> 3) ^ (l15 >> 2)) << 3) + ((l4 & 1) * 4);
  const int exw_off = 16384 + q * 512 + l15 * 32 + exw;
  const int exr_off = 16384 + q * 512 + l15 * 32 + ((l4 ^ (l15 >> 2)) << 3);

  // per-lane global weight bases (wave h's fragment set starts at frag h*8)
  const unsigned char* W1g = w_in8p + (size_t)h * 8 * 512 + lane * 8;
  const unsigned char* W2g = w_out8p + (size_t)h * 8 * 512 + lane * 8;

  for (int ch = 0; ch < NCH; ++ch) {
    if (ch) __syncthreads();  // Texch(ch-1) visible; old Texch slot free

    // ---- a2 read (Texch(ch-1)) ----
    i64 a2 = 0;
    if (ch) a2 = *(const i64*)(smem + exr_off + ((ch - 1) & 1) * 2048);

    // ---- W1(ch) frags from global (coalesced, L1/L2-hot) ----
    i64 w1f[8];
    #pragma unroll
    for (int kk = 0; kk < 8; ++kk)
      w1f[kk] = *(const i64*)(W1g + (size_t)ch * 8192 + kk * 512);

    // ---- GEMM1(ch): two independent K-chains ----
    f32x4 acc1a = {}, acc1b = {};
    __builtin_amdgcn_s_setprio(1);
    #pragma unroll
    for (int kk = 0; kk < 4; ++kk) {
      acc1a = __builtin_amdgcn_mfma_f32_16x16x32_fp8_fp8(w1f[kk], breg[kk], acc1a, 0, 0, 0);
      acc1b = __builtin_amdgcn_mfma_f32_16x16x32_fp8_fp8(w1f[4 + kk], breg[4 + kk], acc1b, 0, 0, 0);
    }
    __builtin_amdgcn_s_setprio(0);

    // ---- W2(ch-1) frags from global, issued before GELU (latency under GELU) ----
    i64 w2f[8];
    if (ch) {
      #pragma unroll
      for (int cti = 0; cti < 8; ++cti)
        w2f[cti] = *(const i64*)(W2g + (size_t)(ch - 1) * 8192 + cti * 512);
    }

    // ---- GELU (sum the chains) -> packed fp8 -> Texch slot ch&1 ----
    {
      const float4 bi = *(const float4*)&b_in[ch * 32 + h * 16 + l4 * 4];
      float g[4];
      #pragma unroll
      for (int r = 0; r < 4; ++r) {
        float t = acc1a[r] + acc1b[r] + ((const float*)&bi)[r];
        g[r] = t * __builtin_amdgcn_rcpf(1.0f + __expf(-1.702f * t));
      }
      int pk = __builtin_amdgcn_cvt_pk_fp8_f32(g[0], g[1], 0, false);
      pk = __builtin_amdgcn_cvt_pk_fp8_f32(g[2], g[3], pk, true);
      *(int*)(smem + exw_off + (ch & 1) * 2048) = pk;
    }

    // ---- GEMM2(ch-1): 8 independent MFMAs, pre-barrier tail ----
    if (ch) {
      __builtin_amdgcn_s_setprio(1);
      #pragma unroll
      for (int cti = 0; cti < 8; ++cti)
        acc2[cti] = __builtin_amdgcn_mfma_f32_16x16x32_fp8_fp8(a2, w2f[cti], acc2[cti], 0, 0, 0);
      __builtin_amdgcn_s_setprio(0);
    }
  }

  // ---- drain GEMM2 for last chunk ----
  __syncthreads();
  {
    const i64 a2 = *(const i64*)(smem + exr_off + ((NCH - 1) & 1) * 2048);
    #pragma unroll
    for (int cti = 0; cti < 8; ++cti) {
      i64 b2 = *(const i64*)(W2g + (size_t)(NCH - 1) * 8192 + cti * 512);
      acc2[cti] = __builtin_amdgcn_mfma_f32_16x16x32_fp8_fp8(a2, b2, acc2[cti], 0, 0, 0);
    }
  }

  // ---- epilogue: out = x + gamma_c * (v + b_out_c) ----
  #pragma unroll
  for (int cti = 0; cti < 8; ++cti) {
    int cc = h * 128 + cti * 16 + l15;
    float gm = gamma[cc], bo = b_out[cc];
    int p = p0 + strip + l4 * 4;
    size_t off = xbase + (size_t)cc * HW + p;
    float4 xv = *(const float4*)(x + off);
    float4 o;
    #pragma unroll
    for (int r = 0; r < 4; ++r)
      ((float*)&o)[r] = ((const float*)&xv)[r] + gm * (acc2[cti][r] + bo);
    *(float4*)(out + off) = o;
  }
}

extern "C" void kernel_launch(void* const* d_in, const int* in_sizes, int n_in,
                              void* d_out, int out_size, void* d_ws, size_t ws_size,
                              hipStream_t stream) {
  const float* x = (const float*)d_in[0];
  const float* ln_w = (const float*)d_in[1];
  const float* ln_b = (const float*)d_in[2];
  const float* w_in = (const float*)d_in[3];
  const float* b_in = (const float*)d_in[4];
  const float* w_out = (const float*)d_in[5];
  const float* b_out = (const float*)d_in[6];
  const float* gamma = (const float*)d_in[7];
  float* out = (float*)d_out;

  char* ws = (char*)d_ws;
  unsigned char* w_in8p = (unsigned char*)ws;              // 256 KB frag-packed
  unsigned char* w_out8p = (unsigned char*)(ws + 262144);  // 256 KB frag-packed
  double* partial = (double*)(ws + 524288);                // 8 KB
  float* stats = (float*)(ws + 524288 + 8192);             // 512 B

  k_prep_stats<<<1024, 256, 0, stream>>>(x, w_in, w_out, w_in8p, w_out8p, partial);
  k_stats2<<<1, 64, 0, stream>>>(partial, stats);

  k_fused<<<2048, 512, 0, stream>>>(x, ln_w, ln_b, b_in, b_out, gamma,
                                    w_in8p, w_out8p, stats, out);
}

// Round 15
// 169.842 us; speedup vs baseline: 2.4852x; 2.4852x over previous
//
#include <hip/hip_runtime.h>
#include <math.h>

// x: (4,16,256,32,64) f32 -> NS=64 samples, CD=256 channels, HW=2048 positions
#define NS 64
#define CD 256
#define HW 2048
#define MD 1024
#define SAMPLE (CD * HW)
#define LN_EPS 1e-5f

#define PB 64            // positions per block (4 pair-strips x 16p)
#define MC 32            // m-chunk
#define NCH (MD / MC)    // 32 chunks

typedef float f32x4 __attribute__((ext_vector_type(4)));
typedef long i64;
typedef long i64x2 __attribute__((ext_vector_type(2)));

// Rotated 4-bit XOR swizzle for Ysh (bits 3-6).
__device__ __forceinline__ int swz(int p) {
  int k = (p ^ (p >> 2)) & 15;
  return ((k & 7) << 4) | (k & 8);
}

__device__ __forceinline__ void gl_lds16(const unsigned char* g, unsigned char* l) {
  __builtin_amdgcn_global_load_lds(
      (const __attribute__((address_space(1))) unsigned char*)g,
      (__attribute__((address_space(3))) unsigned char*)l, 16, 0, 0);
}

// ------------- merged: weight prep (fp8, PAIRED-frag-packed) + LN stats stage 1 -------------
// blocks 0..511: stats1; blocks 512..1023: prep.
// W1 layout: byte ch*8192 + h*4096 + (kk>>1)*1024 + lane*16 + (kk&1)*8
//   = w_in[c = kk*32+(lane>>4)*8+j][m = ch*32+h*16+(lane&15)]   (kk 0..7, h = m-half)
// W2 layout: byte ch*8192 + h*4096 + (ct>>1)*1024 + lane*16 + (ct&1)*8
//   = w_out[m = ch*32+(lane>>4)*8+j][c = h*128+ct*16+(lane&15)] (ct 0..7, h = c-half)
// -> one ds_read_b128 per fragment PAIR (lane*16 contiguous).
__global__ __launch_bounds__(256) void k_prep_stats(
    const float* __restrict__ x, const float* __restrict__ w_in,
    const float* __restrict__ w_out, unsigned char* __restrict__ w_in8p,
    unsigned char* __restrict__ w_out8p, double* __restrict__ partial) {
  if (blockIdx.x < 512) {
    int s = blockIdx.x >> 3, sl = blockIdx.x & 7;
    const float4* p = (const float4*)(x + (size_t)s * SAMPLE + (size_t)sl * 65536);
    double sum = 0.0, ssq = 0.0;
    for (int i = 0; i < 64; ++i) {
      float4 v = p[i * 256 + threadIdx.x];
      sum += (double)v.x + (double)v.y + (double)v.z + (double)v.w;
      ssq += (double)v.x * v.x + (double)v.y * v.y + (double)v.z * v.z + (double)v.w * v.w;
    }
    for (int off = 32; off; off >>= 1) {
      sum += __shfl_down(sum, off);
      ssq += __shfl_down(ssq, off);
    }
    __shared__ double red[4][2];
    int wv = threadIdx.x >> 6, ln = threadIdx.x & 63;
    if (ln == 0) { red[wv][0] = sum; red[wv][1] = ssq; }
    __syncthreads();
    if (threadIdx.x == 0) {
      for (int i = 1; i < 4; ++i) { sum += red[i][0]; ssq += red[i][1]; }
      partial[blockIdx.x * 2] = sum;
      partial[blockIdx.x * 2 + 1] = ssq;
    }
  } else {
    int id = (blockIdx.x - 512) * 256 + threadIdx.x;  // 0..131071, one int (4B) each
    int off = id << 2;                                 // byte offset in target array
    int ch = off >> 13, r = off & 8191;
    int h = r >> 12; r &= 4095;
    int pr = r >> 10; r &= 1023;
    int lane = r >> 4; r &= 15;
    int lo = r >> 3, j0 = r & 7;                       // j0 in {0,4}
    int kk = pr * 2 + lo;
    if (id < 65536) {
      int m = ch * 32 + h * 16 + (lane & 15);
      int c0 = kk * 32 + (lane >> 4) * 8 + j0;
      float a = w_in[(size_t)(c0 + 0) * MD + m];
      float b = w_in[(size_t)(c0 + 1) * MD + m];
      float c = w_in[(size_t)(c0 + 2) * MD + m];
      float d = w_in[(size_t)(c0 + 3) * MD + m];
      int rr = __builtin_amdgcn_cvt_pk_fp8_f32(a, b, 0, false);
      rr = __builtin_amdgcn_cvt_pk_fp8_f32(c, d, rr, true);
      *(int*)(w_in8p + off) = rr;
    } else {
      // recompute fields for the W2 half (off relative to w_out8p)
      off = (id - 65536) << 2;
      ch = off >> 13; r = off & 8191;
      h = r >> 12; r &= 4095;
      pr = r >> 10; r &= 1023;
      lane = r >> 4; r &= 15;
      lo = r >> 3; j0 = r & 7;
      int ct = pr * 2 + lo;
      int c = h * 128 + ct * 16 + (lane & 15);
      int m0 = ch * 32 + (lane >> 4) * 8 + j0;
      float a = w_out[(size_t)(m0 + 0) * CD + c];
      float b = w_out[(size_t)(m0 + 1) * CD + c];
      float cc = w_out[(size_t)(m0 + 2) * CD + c];
      float d = w_out[(size_t)(m0 + 3) * CD + c];
      int rr = __builtin_amdgcn_cvt_pk_fp8_f32(a, b, 0, false);
      rr = __builtin_amdgcn_cvt_pk_fp8_f32(cc, d, rr, true);
      *(int*)(w_out8p + off) = rr;
    }
  }
}

// ---------------- fused LN + MLP + layer-scale + residual ----------------
// r13 structure exactly (PB=64, 8 waves = 4 p-strips x 2 halves, 3 blocks/CU,
// deferred GEMM2, Texch swizzled pair-handoff, weight LDS dbuf/tribuf via
// global_load_lds) with: (a) paired-fragment ds_read_b128 weight reads
// (16 -> 8 LDS instrs/wave/chunk, b128 = best LDS width), (b) stats2 inlined
// (one launch fewer; 16 uniform doubles per block).
__global__ __launch_bounds__(512, 6) void k_fused(
    const float* __restrict__ x, const float* __restrict__ ln_w, const float* __restrict__ ln_b,
    const float* __restrict__ b_in, const float* __restrict__ b_out, const float* __restrict__ gamma,
    const unsigned char* __restrict__ w_in8p, const unsigned char* __restrict__ w_out8p,
    const double* __restrict__ partial, float* __restrict__ out) {
  __shared__ unsigned char smem[45056];   // [0,24K) W2 x3 | [24K,40K) W1 x2 | [40K,44K) Texch x2
  unsigned char* Ysh = smem + 8192;       // [64][256] fp8 swizzled, overlays W2 slots 1-2

  const int tid = threadIdx.x;
  const int lane = tid & 63, l15 = lane & 15, l4 = lane >> 4;
  const int wv = tid >> 6;                 // 0..7
  const int q = wv >> 1, h = wv & 1;       // pair, c/m half
  const int s = blockIdx.x >> 5;
  const int p0 = (blockIdx.x & 31) * PB;
  const size_t xbase = (size_t)s * SAMPLE;

  // ---- inline stats2: sample s's mean/rstd from 8 partial pairs (uniform) ----
  double sum = 0.0, ssq = 0.0;
  #pragma unroll
  for (int i = 0; i < 8; ++i) {
    sum += partial[s * 16 + i * 2];
    ssq += partial[s * 16 + i * 2 + 1];
  }
  double mean = sum / (double)SAMPLE;
  double var = ssq / (double)SAMPLE - mean * mean;
  const float rstd = (float)(1.0 / sqrt(var + (double)LN_EPS));
  const float a_ln = rstd, c_ln = -(float)mean * rstd;

  // ---- prefetch chunk-0 weights into non-Ysh slots (hide under staging) ----
  gl_lds16(w_in8p + wv * 1024 + lane * 16, smem + 24576 + wv * 1024);   // W1 slot0
  gl_lds16(w_out8p + wv * 1024 + lane * 16, smem + wv * 1024);          // W2 slot0

  // ---- stage Ysh: normalize + affine, transpose (c,p)->(p,c), cvt fp8 ----
  #pragma unroll
  for (int it = 0; it < 2; ++it) {
    int bid = it * 512 + tid;               // 1024 4x4 micro-blocks
    int c0 = (bid >> 4) * 4, pp = (bid & 15) * 4;
    float yv[4][4];
    #pragma unroll
    for (int i = 0; i < 4; ++i) {
      size_t off = (size_t)(c0 + i) * HW + p0 + pp;
      float4 xv = *(const float4*)(x + xbase + off);
      float4 lw = *(const float4*)(ln_w + off);
      float4 lb = *(const float4*)(ln_b + off);
      yv[i][0] = fmaf(fmaf(xv.x, a_ln, c_ln), lw.x, lb.x);
      yv[i][1] = fmaf(fmaf(xv.y, a_ln, c_ln), lw.y, lb.y);
      yv[i][2] = fmaf(fmaf(xv.z, a_ln, c_ln), lw.z, lb.z);
      yv[i][3] = fmaf(fmaf(xv.w, a_ln, c_ln), lw.w, lb.w);
    }
    #pragma unroll
    for (int j = 0; j < 4; ++j) {
      int p = pp + j;
      int r = __builtin_amdgcn_cvt_pk_fp8_f32(yv[0][j], yv[1][j], 0, false);
      r = __builtin_amdgcn_cvt_pk_fp8_f32(yv[2][j], yv[3][j], r, true);
      *(int*)&Ysh[p * 256 + (c0 ^ swz(p))] = r;
    }
  }

  const int strip = q * 16;                // pair's p-strip
  const int pY = strip + l15;
  const int sY = swz(pY);
  f32x4 acc2[8] = {};                      // 16p x 128c per wave (8 c-tiles)

  __syncthreads();  // Ysh visible; chunk-0 weight DMA drained

  // ---- breg: the pair's ENTIRE Ysh slice -> 8 i64 registers ----
  i64 breg[8];
  #pragma unroll
  for (int kk = 0; kk < 8; ++kk)
    breg[kk] = *(const i64*)&Ysh[pY * 256 + ((kk * 32 + l4 * 8) ^ sY)];

  __syncthreads();  // all breg reads done -> Ysh region reusable by DMA

  // Texch addressing (r13-verified swizzle)
  const int exw = ((((h * 16 + l4 * 4) >> 3) ^ (l15 >> 2)) << 3) + ((l4 & 1) * 4);
  const int exw_off = 40960 + q * 512 + l15 * 32 + exw;
  const int exr_off = 40960 + q * 512 + l15 * 32 + ((l4 ^ (l15 >> 2)) << 3);

  for (int ch = 0; ch < NCH; ++ch) {
    if (ch) __syncthreads();  // prefetch(ch) drained; old slots free; Texch(ch-1) visible

    // ---- prefetch chunk ch+1: W1 -> slot (ch+1)&1, W2 -> slot (ch+1)%3 ----
    if (ch + 1 < NCH) {
      const size_t co = (size_t)(ch + 1) * 8192;
      gl_lds16(w_in8p + co + wv * 1024 + lane * 16,
               smem + 24576 + ((ch + 1) & 1) * 8192 + wv * 1024);
      gl_lds16(w_out8p + co + wv * 1024 + lane * 16,
               smem + ((ch + 1) % 3) * 8192 + wv * 1024);
    }

    // ---- a2 read (Texch(ch-1), visible since barrier) ----
    i64 a2 = 0;
    if (ch) a2 = *(const i64*)(smem + ((ch - 1) & 1) * 2048 + exr_off);

    // ---- GEMM1(ch): paired b128 W1 reads, two independent K-chains ----
    const unsigned char* W1 = smem + 24576 + (ch & 1) * 8192 + h * 4096;
    f32x4 acc1a = {}, acc1b = {};
    __builtin_amdgcn_s_setprio(1);
    #pragma unroll
    for (int kp = 0; kp < 4; ++kp) {
      i64x2 w = *(const i64x2*)&W1[kp * 1024 + lane * 16];
      acc1a = __builtin_amdgcn_mfma_f32_16x16x32_fp8_fp8(w.x, breg[kp * 2], acc1a, 0, 0, 0);
      acc1b = __builtin_amdgcn_mfma_f32_16x16x32_fp8_fp8(w.y, breg[kp * 2 + 1], acc1b, 0, 0, 0);
    }
    __builtin_amdgcn_s_setprio(0);

    // ---- GELU (sum the chains) -> packed fp8 -> Texch slot ch&1 ----
    {
      const float4 bi = *(const float4*)&b_in[ch * 32 + h * 16 + l4 * 4];
      float g[4];
      #pragma unroll
      for (int r = 0; r < 4; ++r) {
        float t = acc1a[r] + acc1b[r] + ((const float*)&bi)[r];
        g[r] = t * __builtin_amdgcn_rcpf(1.0f + __expf(-1.702f * t));
      }
      int pk = __builtin_amdgcn_cvt_pk_fp8_f32(g[0], g[1], 0, false);
      pk = __builtin_amdgcn_cvt_pk_fp8_f32(g[2], g[3], pk, true);
      *(int*)(smem + (ch & 1) * 2048 + exw_off) = pk;
    }

    // ---- GEMM2(ch-1): paired b128 W2 reads, 8 independent MFMAs ----
    if (ch) {
      const unsigned char* W2 = smem + ((ch - 1) % 3) * 8192 + h * 4096;
      __builtin_amdgcn_s_setprio(1);
      #pragma unroll
      for (int cp = 0; cp < 4; ++cp) {
        i64x2 w = *(const i64x2*)&W2[cp * 1024 + lane * 16];
        acc2[cp * 2] = __builtin_amdgcn_mfma_f32_16x16x32_fp8_fp8(a2, w.x, acc2[cp * 2], 0, 0, 0);
        acc2[cp * 2 + 1] = __builtin_amdgcn_mfma_f32_16x16x32_fp8_fp8(a2, w.y, acc2[cp * 2 + 1], 0, 0, 0);
      }
      __builtin_amdgcn_s_setprio(0);
    }
  }

  // ---- drain GEMM2 for last chunk (Texch written this iter -> barrier first) ----
  __syncthreads();
  {
    const i64 a2 = *(const i64*)(smem + ((NCH - 1) & 1) * 2048 + exr_off);
    const unsigned char* W2 = smem + ((NCH - 1) % 3) * 8192 + h * 4096;
    #pragma unroll
    for (int cp = 0; cp < 4; ++cp) {
      i64x2 w = *(const i64x2*)&W2[cp * 1024 + lane * 16];
      acc2[cp * 2] = __builtin_amdgcn_mfma_f32_16x16x32_fp8_fp8(a2, w.x, acc2[cp * 2], 0, 0, 0);
      acc2[cp * 2 + 1] = __builtin_amdgcn_mfma_f32_16x16x32_fp8_fp8(a2, w.y, acc2[cp * 2 + 1], 0, 0, 0);
    }
  }

  // ---- epilogue: out = x + gamma_c * (v + b_out_c) ----
  #pragma unroll
  for (int cti = 0; cti < 8; ++cti) {
    int cc = h * 128 + cti * 16 + l15;
    float gm = gamma[cc], bo = b_out[cc];
    int p = p0 + strip + l4 * 4;
    size_t off = xbase + (size_t)cc * HW + p;
    float4 xv = *(const float4*)(x + off);
    float4 o;
    #pragma unroll
    for (int r = 0; r < 4; ++r)
      ((float*)&o)[r] = ((const float*)&xv)[r] + gm * (acc2[cti][r] + bo);
    *(float4*)(out + off) = o;
  }
}

extern "C" void kernel_launch(void* const* d_in, const int* in_sizes, int n_in,
                              void* d_out, int out_size, void* d_ws, size_t ws_size,
                              hipStream_t stream) {
  const float* x = (const float*)d_in[0];
  const float* ln_w = (const float*)d_in[1];
  const float* ln_b = (const float*)d_in[2];
  const float* w_in = (const float*)d_in[3];
  const float* b_in = (const float*)d_in[4];
  const float* w_out = (const float*)d_in[5];
  const float* b_out = (const float*)d_in[6];
  const float* gamma = (const float*)d_in[7];
  float* out = (float*)d_out;

  char* ws = (char*)d_ws;
  unsigned char* w_in8p = (unsigned char*)ws;              // 256 KB paired-frag-packed
  unsigned char* w_out8p = (unsigned char*)(ws + 262144);  // 256 KB paired-frag-packed
  double* partial = (double*)(ws + 524288);                // 8 KB

  k_prep_stats<<<1024, 256, 0, stream>>>(x, w_in, w_out, w_in8p, w_out8p, partial);

  k_fused<<<2048, 512, 0, stream>>>(x, ln_w, ln_b, b_in, b_out, gamma,
                                    w_in8p, w_out8p, partial, out);
}